// Round 1
// baseline (81.893 us; speedup 1.0000x reference)
//
#include <hip/hip_runtime.h>

// LocallyConnected2D: out[b,p,f] = sum_k x_patch[b,p,k] * kernel[p,k,f] + bias[p,f]
// B=16, H=W=64, C=32, KH=KW=3, OH=OW=62, P=3844, K=288, F=64, all fp32.
//
// Weight tensor (283 MB) dominates traffic -> stream it exactly once:
// each thread holds ALL 16 batches in registers (float4 acc[16]), so every
// weight float4 is loaded once from HBM and used 16 times. Lanes split F
// (16 quads); 16 p's per 256-thread block.

namespace {
constexpr int BDIM = 16;
constexpr int Hc = 64, Wc = 64, Cc = 32;
constexpr int OWc = 62;
constexpr int Pc = 62 * 62;   // 3844
constexpr int Fc = 64;
constexpr int Kc = 9 * Cc;    // 288
constexpr int PPB = 16;       // p's per block
}

__global__ __launch_bounds__(256, 1)
void lc2d(const float* __restrict__ x, const float* __restrict__ kern,
          const float* __restrict__ bias, float* __restrict__ out)
{
    const int t  = threadIdx.x;
    const int fq = t & 15;        // which f-quad this lane owns
    const int f0 = fq << 2;
    const int p  = blockIdx.x * PPB + (t >> 4);
    if (p >= Pc) return;
    const int oh = p / OWc;
    const int ow = p - oh * OWc;

    const float* kbase = kern + (size_t)p * Kc * Fc + f0;

    float4 acc[BDIM];
    const float4 bv = *(const float4*)(bias + (size_t)p * Fc + f0);
    #pragma unroll
    for (int b = 0; b < BDIM; ++b) acc[b] = bv;

    #pragma unroll
    for (int kh = 0; kh < 3; ++kh) {
      #pragma unroll
      for (int kw = 0; kw < 3; ++kw) {
        // x[b, oh+kh, ow+kw, c]; c contiguous (32 floats)
        const float* xb = x + ((size_t)(oh + kh) * Wc + (ow + kw)) * Cc;
        // kernel[p, k, f] with k = kh*96 + kw*32 + c
        const float* kk = kbase + (size_t)(kh * 96 + kw * 32) * Fc;
        #pragma unroll 2
        for (int c4 = 0; c4 < 8; ++c4) {
          const float4 kv0 = *(const float4*)(kk + (c4 * 4 + 0) * Fc);
          const float4 kv1 = *(const float4*)(kk + (c4 * 4 + 1) * Fc);
          const float4 kv2 = *(const float4*)(kk + (c4 * 4 + 2) * Fc);
          const float4 kv3 = *(const float4*)(kk + (c4 * 4 + 3) * Fc);
          #pragma unroll
          for (int b = 0; b < BDIM; ++b) {
            const float4 xv = *(const float4*)(xb + (size_t)b * (Hc * Wc * Cc) + c4 * 4);
            acc[b].x = fmaf(xv.x, kv0.x, fmaf(xv.y, kv1.x, fmaf(xv.z, kv2.x, fmaf(xv.w, kv3.x, acc[b].x))));
            acc[b].y = fmaf(xv.x, kv0.y, fmaf(xv.y, kv1.y, fmaf(xv.z, kv2.y, fmaf(xv.w, kv3.y, acc[b].y))));
            acc[b].z = fmaf(xv.x, kv0.z, fmaf(xv.y, kv1.z, fmaf(xv.z, kv2.z, fmaf(xv.w, kv3.z, acc[b].z))));
            acc[b].w = fmaf(xv.x, kv0.w, fmaf(xv.y, kv1.w, fmaf(xv.z, kv2.w, fmaf(xv.w, kv3.w, acc[b].w))));
          }
        }
      }
    }

    // out[b, p, f] = (b*P + p)*F + f
    #pragma unroll
    for (int b = 0; b < BDIM; ++b)
      *(float4*)(out + ((size_t)b * Pc + p) * Fc + f0) = acc[b];
}

extern "C" void kernel_launch(void* const* d_in, const int* in_sizes, int n_in,
                              void* d_out, int out_size, void* d_ws, size_t ws_size,
                              hipStream_t stream)
{
    const float* x    = (const float*)d_in[0];
    const float* kern = (const float*)d_in[1];
    const float* bias = (const float*)d_in[2];
    float* out = (float*)d_out;
    dim3 grid((Pc + PPB - 1) / PPB);
    lc2d<<<grid, 256, 0, stream>>>(x, kern, bias, out);
}